// Round 1
// baseline (190.465 us; speedup 1.0000x reference)
//
#include <hip/hip_runtime.h>
#include <stdint.h>

#define NPTS 4096
#define NC 128
#define NB 8

typedef __bf16 bf16x8 __attribute__((ext_vector_type(8)));
typedef float f32x4 __attribute__((ext_vector_type(4)));
typedef unsigned short u16;
typedef unsigned int u32;

__device__ inline u16 f2bf(float x) {
    u32 u = __float_as_uint(x);
    u32 r = (u + 0x7fffu + ((u >> 16) & 1u)) >> 16;
    return (u16)r;
}

// Kernel 1: normalize points, write bf16 [B][N][C] row-major into workspace.
// features layout is [B][C][N]; read coalesced over n, transpose via LDS.
__global__ __launch_bounds__(256) void normalize_kernel(const float* __restrict__ feat,
                                                        u16* __restrict__ vbf) {
    int b = blockIdx.y;
    int n0 = blockIdx.x * 64;
    int tid = threadIdx.x;
    int tx = tid & 63, ty = tid >> 6;  // tx: point-in-tile, ty: c-group
    __shared__ float tile[64][129];    // +1 pad: write is 2-way (free), read 4-way
    __shared__ float part[4][64];
    __shared__ float rn[64];
    const float* fb = feat + (size_t)b * NC * NPTS;
    float ssq = 0.f;
#pragma unroll
    for (int i = 0; i < 32; ++i) {
        int c = ty * 32 + i;
        float x = fb[(size_t)c * NPTS + n0 + tx];  // coalesced over tx
        tile[tx][c] = x;
        ssq += x * x;
    }
    part[ty][tx] = ssq;
    __syncthreads();
    if (ty == 0) {
        float s = part[0][tx] + part[1][tx] + part[2][tx] + part[3][tx];
        rn[tx] = 1.f / fmaxf(sqrtf(s), 1e-12f);  // F.normalize eps semantics
    }
    __syncthreads();
    u32* out = (u32*)vbf;
    size_t obase = ((size_t)b * NPTS + n0) * (NC / 2);
#pragma unroll
    for (int i = 0; i < 16; ++i) {
        int idx = tid + i * 256;       // 64 pts x 64 uints, coalesced store
        int p = idx >> 6, k = idx & 63;
        float r = rn[p];
        float x0 = tile[p][2 * k] * r;
        float x1 = tile[p][2 * k + 1] * r;
        u32 u = (u32)f2bf(x0) | ((u32)f2bf(x1) << 16);
        out[obase + (size_t)p * 64 + k] = u;
    }
}

// Kernel 2: per-cloud label histogram (labels in [0,16))
__global__ __launch_bounds__(256) void count_kernel(const int* __restrict__ labels,
                                                    int* __restrict__ counts) {
    int b = blockIdx.x;
    __shared__ int h[16];
    if (threadIdx.x < 16) h[threadIdx.x] = 0;
    __syncthreads();
    for (int n = threadIdx.x; n < NPTS; n += 256)
        atomicAdd(&h[labels[b * NPTS + n] & 15], 1);
    __syncthreads();
    if (threadIdx.x < 16) counts[b * 16 + threadIdx.x] = h[threadIdx.x];
}

// Kernel 3: fused similarity + exp + masked row reduction.
// Block: 256 thr = 4 waves, 64 rows (16 rows/wave). Col loop stages 64-point
// tiles into LDS (row stride 136 bf16 = +16B pad -> B-frag ds_read_b128 is
// 2-way conflict = free). MFMA f32_16x16x32_bf16: A[m=lane&15][k=quad*8+j],
// B[k][n=lane&15] same per-point layout; D: col=lane&15, row=quad*4+reg.
__global__ __launch_bounds__(256) void sim_kernel(const u16* __restrict__ vbf,
                                                  const int* __restrict__ labels,
                                                  const int* __restrict__ counts,
                                                  float* __restrict__ acc) {
    int b = blockIdx.y;
    int row0 = blockIdx.x * 64;
    int tid = threadIdx.x;
    int wave = tid >> 6, lane = tid & 63;
    int quad = lane >> 4, ln = lane & 15;

    const u16* vb = vbf + (size_t)b * NPTS * NC;
    const int* lab = labels + b * NPTS;

    // A fragments for this wave's 16 rows, K=128 (held across whole col loop)
    int arow = row0 + wave * 16 + ln;
    bf16x8 afrag[4];
#pragma unroll
    for (int f = 0; f < 4; ++f)
        afrag[f] = *(const bf16x8*)(vb + (size_t)arow * NC + f * 32 + quad * 8);

    int growbase = row0 + wave * 16 + quad * 4;  // this lane's 4 D-rows
    int lrow[4];
#pragma unroll
    for (int r = 0; r < 4; ++r) lrow[r] = lab[growbase + r];

    float pos[4] = {0.f, 0.f, 0.f, 0.f};
    float neg[4] = {0.f, 0.f, 0.f, 0.f};

    __shared__ u16 cols[64 * 136];
    __shared__ int clab[64];

    for (int ct = 0; ct < NPTS; ct += 64) {
        __syncthreads();
        // stage 64 col-points (128 bf16 each) into LDS, padded rows
        const uint4* src = (const uint4*)(vb + (size_t)ct * NC);
#pragma unroll
        for (int i = 0; i < 4; ++i) {
            int idx = tid + i * 256;          // 1024 x 16B, coalesced global
            int rr = idx >> 4, cc = idx & 15;
            *(uint4*)(cols + rr * 136 + cc * 8) = src[idx];
        }
        if (tid < 64) clab[tid] = lab[ct + tid];
        __syncthreads();

#pragma unroll
        for (int sub = 0; sub < 4; ++sub) {
            const u16* cp = cols + (sub * 16 + ln) * 136 + quad * 8;
            f32x4 d = {0.f, 0.f, 0.f, 0.f};
#pragma unroll
            for (int f = 0; f < 4; ++f) {
                bf16x8 bfrag = *(const bf16x8*)(cp + f * 32);
                d = __builtin_amdgcn_mfma_f32_16x16x32_bf16(afrag[f], bfrag, d, 0, 0, 0);
            }
            int gcol = ct + sub * 16 + ln;
            int lc = clab[sub * 16 + ln];
#pragma unroll
            for (int r = 0; r < 4; ++r) {
                float e = __expf(d[r]);
                bool same = (lc == lrow[r]);
                bool diag = (gcol == growbase + r);  // diag zeroed in reference
                pos[r] += (same && !diag) ? e : 0.f;
                neg[r] += same ? 0.f : e;
            }
        }
    }

    // reduce across the 16 lanes of each quad (xor masks 1..8 stay in-group)
#pragma unroll
    for (int off = 1; off < 16; off <<= 1) {
#pragma unroll
        for (int r = 0; r < 4; ++r) {
            pos[r] += __shfl_xor(pos[r], off);
            neg[r] += __shfl_xor(neg[r], off);
        }
    }
    if (ln == 0) {
        const int* cnt = counts + b * 16;
        float lsum = 0.f;
#pragma unroll
        for (int r = 0; r < 4; ++r) {
            int cp = cnt[lrow[r]];           // includes self, as in reference
            float p = pos[r] / (float)cp;
            float n = neg[r] / (float)(NPTS - cp);
            lsum += -__logf(p / (p + n));    // 1/TEMP cancels in the ratio
        }
        atomicAdd(acc, lsum);
    }
}

__global__ void final_kernel(const float* __restrict__ acc, float* __restrict__ out) {
    out[0] = acc[0] * (1.f / (float)(NB * NPTS));
}

extern "C" void kernel_launch(void* const* d_in, const int* in_sizes, int n_in,
                              void* d_out, int out_size, void* d_ws, size_t ws_size,
                              hipStream_t stream) {
    const float* feat = (const float*)d_in[0];
    const int* labels = (const int*)d_in[1];
    float* out = (float*)d_out;

    float* acc = (float*)d_ws;                      // 4 B
    int* counts = (int*)((char*)d_ws + 256);        // 512 B
    u16* vbf = (u16*)((char*)d_ws + 4096);          // 8 MB bf16 [B][N][C]

    hipMemsetAsync(d_ws, 0, 1024, stream);          // zero acc (+counts slab)
    normalize_kernel<<<dim3(NPTS / 64, NB), 256, 0, stream>>>(feat, vbf);
    count_kernel<<<dim3(NB), 256, 0, stream>>>(labels, counts);
    sim_kernel<<<dim3(NPTS / 64, NB), 256, 0, stream>>>(vbf, labels, counts, acc);
    final_kernel<<<1, 1, 0, stream>>>(acc, out);
}

// Round 2
// 142.126 us; speedup vs baseline: 1.3401x; 1.3401x over previous
//
#include <hip/hip_runtime.h>
#include <stdint.h>

#define NPTS 4096
#define NC 128
#define NB 8
#define CSPLIT 4
#define COLS_PER (NPTS / CSPLIT)  // 1024

typedef __bf16 bf16x8 __attribute__((ext_vector_type(8)));
typedef float f32x4 __attribute__((ext_vector_type(4)));
typedef unsigned short u16;
typedef unsigned int u32;

__device__ inline u16 f2bf(float x) {
    u32 u = __float_as_uint(x);
    u32 r = (u + 0x7fffu + ((u >> 16) & 1u)) >> 16;
    return (u16)r;
}

// Kernel 1: normalize points, write bf16 [B][N][C] row-major into workspace.
__global__ __launch_bounds__(256) void normalize_kernel(const float* __restrict__ feat,
                                                        u16* __restrict__ vbf) {
    int b = blockIdx.y;
    int n0 = blockIdx.x * 64;
    int tid = threadIdx.x;
    int tx = tid & 63, ty = tid >> 6;
    __shared__ float tile[64][129];
    __shared__ float part[4][64];
    __shared__ float rn[64];
    const float* fb = feat + (size_t)b * NC * NPTS;
    float ssq = 0.f;
#pragma unroll
    for (int i = 0; i < 32; ++i) {
        int c = ty * 32 + i;
        float x = fb[(size_t)c * NPTS + n0 + tx];
        tile[tx][c] = x;
        ssq += x * x;
    }
    part[ty][tx] = ssq;
    __syncthreads();
    if (ty == 0) {
        float s = part[0][tx] + part[1][tx] + part[2][tx] + part[3][tx];
        rn[tx] = 1.f / fmaxf(sqrtf(s), 1e-12f);
    }
    __syncthreads();
    u32* out = (u32*)vbf;
    size_t obase = ((size_t)b * NPTS + n0) * (NC / 2);
#pragma unroll
    for (int i = 0; i < 16; ++i) {
        int idx = tid + i * 256;
        int p = idx >> 6, k = idx & 63;
        float r = rn[p];
        float x0 = tile[p][2 * k] * r;
        float x1 = tile[p][2 * k + 1] * r;
        u32 u = (u32)f2bf(x0) | ((u32)f2bf(x1) << 16);
        out[obase + (size_t)p * 64 + k] = u;
    }
}

// Kernel 2: per-cloud label histogram (labels in [0,16))
__global__ __launch_bounds__(256) void count_kernel(const int* __restrict__ labels,
                                                    int* __restrict__ counts) {
    int b = blockIdx.x;
    __shared__ int h[16];
    if (threadIdx.x < 16) h[threadIdx.x] = 0;
    __syncthreads();
    for (int n = threadIdx.x; n < NPTS; n += 256)
        atomicAdd(&h[labels[b * NPTS + n] & 15], 1);
    __syncthreads();
    if (threadIdx.x < 16) counts[b * 16 + threadIdx.x] = h[threadIdx.x];
}

// Kernel 3: fused similarity + exp + masked row partial sums.
// 2048 blocks: 64 row-tiles x 4 col-splits x 8 clouds. 64 rows x 1024 cols
// per block. LDS: 64x128 u16 unpadded, 16B chunks XOR-swizzled by row&15 so
// both the staging writes and B-frag ds_read_b128 hit all 32 banks evenly
// (8 cyc / 1024B = minimum). Diagonal handled only in the one tile where
// ct == row0 (wave-uniform branch); neg recovered as sall - psame later.
__global__ __launch_bounds__(256, 8) void sim_kernel(const u16* __restrict__ vbf,
                                                     const int* __restrict__ labels,
                                                     float2* __restrict__ rowacc) {
    int b = blockIdx.y;
    int rt = blockIdx.x >> 2;
    int cs = blockIdx.x & 3;
    int row0 = rt * 64;
    int c0 = cs * COLS_PER;
    int tid = threadIdx.x;
    int wave = tid >> 6, lane = tid & 63;
    int quad = lane >> 4, ln = lane & 15;

    const u16* vb = vbf + (size_t)b * NPTS * NC;
    const int* lab = labels + b * NPTS;

    // A fragments: this wave's 16 rows, full K=128
    int arow = row0 + wave * 16 + ln;
    bf16x8 afrag[4];
#pragma unroll
    for (int f = 0; f < 4; ++f)
        afrag[f] = *(const bf16x8*)(vb + (size_t)arow * NC + f * 32 + quad * 8);

    int growbase = row0 + wave * 16 + quad * 4;
    int lrow[4];
#pragma unroll
    for (int r = 0; r < 4; ++r) lrow[r] = lab[growbase + r];

    float psame[4] = {0.f, 0.f, 0.f, 0.f};
    float sall[4] = {0.f, 0.f, 0.f, 0.f};

    __shared__ u16 cols[64 * 128];
    __shared__ int clab[64];

    for (int ct = c0; ct < c0 + COLS_PER; ct += 64) {
        __syncthreads();
        const uint4* src = (const uint4*)(vb + (size_t)ct * NC);
#pragma unroll
        for (int i = 0; i < 4; ++i) {
            int idx = tid + i * 256;
            int rr = idx >> 4, cc = idx & 15;
            *(uint4*)(cols + rr * 128 + ((cc ^ (rr & 15)) * 8)) = src[idx];
        }
        if (tid < 64) clab[tid] = lab[ct + tid];
        __syncthreads();

        bool diagtile = (ct == row0);
#pragma unroll
        for (int sub = 0; sub < 4; ++sub) {
            const u16* rowbase = cols + (sub * 16 + ln) * 128;
            f32x4 d = {0.f, 0.f, 0.f, 0.f};
#pragma unroll
            for (int f = 0; f < 4; ++f) {
                bf16x8 bfrag = *(const bf16x8*)(rowbase + (((4 * f + quad) ^ ln) * 8));
                d = __builtin_amdgcn_mfma_f32_16x16x32_bf16(afrag[f], bfrag, d, 0, 0, 0);
            }
            int lc = clab[sub * 16 + ln];
            if (diagtile && sub == wave) {
                // diag element for lane: ln == quad*4 + r (same point, same label)
#pragma unroll
                for (int r = 0; r < 4; ++r) {
                    float e = __expf(d[r]);
                    float ee = (ln == quad * 4 + r) ? 0.f : e;
                    sall[r] += ee;
                    psame[r] += (lc == lrow[r]) ? ee : 0.f;
                }
            } else {
#pragma unroll
                for (int r = 0; r < 4; ++r) {
                    float e = __expf(d[r]);
                    sall[r] += e;
                    psame[r] += (lc == lrow[r]) ? e : 0.f;
                }
            }
        }
    }

    // reduce across the 16 lanes of each quad (xor 1,2,4,8 stay in-group)
#pragma unroll
    for (int off = 1; off < 16; off <<= 1) {
#pragma unroll
        for (int r = 0; r < 4; ++r) {
            psame[r] += __shfl_xor(psame[r], off);
            sall[r] += __shfl_xor(sall[r], off);
        }
    }
    if (ln == 0) {
#pragma unroll
        for (int r = 0; r < 4; ++r) {
            float2 v = {psame[r], sall[r]};
            rowacc[((size_t)cs * NB + b) * NPTS + growbase + r] = v;
        }
    }
}

// Kernel 4: per-row finalize + global mean accumulation
__global__ __launch_bounds__(256) void loss_kernel(const float2* __restrict__ rowacc,
                                                   const int* __restrict__ labels,
                                                   const int* __restrict__ counts,
                                                   float* __restrict__ acc) {
    int idx = blockIdx.x * 256 + threadIdx.x;  // 0..B*NPTS-1
    int b = idx >> 12;
    float ps = 0.f, sa = 0.f;
#pragma unroll
    for (int cs = 0; cs < CSPLIT; ++cs) {
        float2 v = rowacc[(size_t)cs * NB * NPTS + idx];
        ps += v.x;
        sa += v.y;
    }
    int lb = labels[idx] & 15;
    int cnt = counts[b * 16 + lb];
    float p = ps / (float)cnt;
    float n = (sa - ps) / (float)(NPTS - cnt);
    float loss = -__logf(p / (p + n));
#pragma unroll
    for (int off = 1; off < 64; off <<= 1) loss += __shfl_xor(loss, off);
    if ((threadIdx.x & 63) == 0) atomicAdd(acc, loss);
}

__global__ void final_kernel(const float* __restrict__ acc, float* __restrict__ out) {
    out[0] = acc[0] * (1.f / (float)(NB * NPTS));
}

extern "C" void kernel_launch(void* const* d_in, const int* in_sizes, int n_in,
                              void* d_out, int out_size, void* d_ws, size_t ws_size,
                              hipStream_t stream) {
    const float* feat = (const float*)d_in[0];
    const int* labels = (const int*)d_in[1];
    float* out = (float*)d_out;

    float* acc = (float*)d_ws;                            // 4 B
    int* counts = (int*)((char*)d_ws + 256);              // 512 B
    float2* rowacc = (float2*)((char*)d_ws + 4096);       // 4*8*4096*8 B = 1 MB
    u16* vbf = (u16*)((char*)d_ws + 4096 + (size_t)CSPLIT * NB * NPTS * 8);  // 8 MB

    hipMemsetAsync(acc, 0, 4, stream);
    normalize_kernel<<<dim3(NPTS / 64, NB), 256, 0, stream>>>(feat, vbf);
    count_kernel<<<dim3(NB), 256, 0, stream>>>(labels, counts);
    sim_kernel<<<dim3((NPTS / 64) * CSPLIT, NB), 256, 0, stream>>>(vbf, labels, rowacc);
    loss_kernel<<<dim3(NB * NPTS / 256), 256, 0, stream>>>(rowacc, labels, counts, acc);
    final_kernel<<<1, 1, 0, stream>>>(acc, out);
}